// Round 3
// baseline (50.301 us; speedup 1.0000x reference)
//
#include <hip/hip_runtime.h>
#include <math.h>

// NormalLoss: for each template vertex (M=6890), take the K=15 scan points
// (N=20000) with LARGEST distance, among them pick the min-angle normal
// match, loss = mean ||sv[sel]-tv||.
//
// Round-9 design: octant-partitioned radial sort (round-8 bound kept: it
// cut knn to ~4 us) with the sort pipeline rebuilt as cheap two-kernel
// hist -> scan_scatter (round-8 ledger: fused per-block prefix
// re-histogram = O(N) serial latency chain per block = 42.9 us, VALUBusy
// 1.6% -> pure latency stall; never re-read all N per block).
//  * hist: each block LDS-histograms ONLY its own 256 points over 2048
//    (octant,shell) buckets, writes its full row (poison-safe overwrite).
//  * scan_scatter: per-thread 8-contiguous-bucket column sums over block
//    rows via int4 loads (coalesced, independent -> pipelined), KS scan,
//    block 0 tabulates rmax[o][k] (+inf top shell: exact-safe) and
//    octStartG, then scatters its own 256 points via LDS cursors.
//  * knn (unchanged from round 8, verified absmax 0.0): per-wave vertex;
//    bound max d^2 over octant suffix = r^2+|tv|^2+2 r g_o (g_o =
//    opposed-component energy; exact Cauchy-Schwarz, direction-aware);
//    bootstrap bitonic in argmax-g octant; sorted-insert top-K with thr
//    re-tightened per insert; *1.00001 fp-safe margin on skips.
//  * reduce: 1-block partial sum (no atomics on out anywhere).

constexpr int K = 15;
constexpr int RBUCK = 256;         // radial shells per octant (0.125-wide |p|^2)
constexpr int NBUCK2 = 8 * RBUCK;  // total buckets
constexpr int WAVES = 4;           // waves (=vertices) per block in main kernel

__device__ __forceinline__ int rbucket_of(float k2) {
    int b = (int)(k2 * 8.0f);
    b = b > (RBUCK - 1) ? (RBUCK - 1) : b;
    return (RBUCK - 1) - b;        // 0 = largest |p| shell
}
__device__ __forceinline__ int octant_of(float x, float y, float z) {
    return (x < 0.0f ? 1 : 0) | (y < 0.0f ? 2 : 0) | (z < 0.0f ? 4 : 0);
}

__global__ __launch_bounds__(256) void hist_kernel(
    const float* __restrict__ sv, int* __restrict__ blkhist, int N)
{
    __shared__ int h[NBUCK2];
    const int t = threadIdx.x;
#pragma unroll
    for (int j = 0; j < 8; ++j) h[t + 256*j] = 0;
    __syncthreads();
    int i = blockIdx.x * 256 + t;
    if (i < N) {
        float x = sv[3*i], y = sv[3*i+1], z = sv[3*i+2];
        int b = (octant_of(x, y, z) << 8) |
                rbucket_of(fmaf(x, x, fmaf(y, y, z*z)));
        atomicAdd(&h[b], 1);
    }
    __syncthreads();
    // full-row overwrite (poison-safe); strided LDS reads are conflict-free,
    // global stores coalesced per j
#pragma unroll
    for (int j = 0; j < 8; ++j)
        blkhist[blockIdx.x * NBUCK2 + t + 256*j] = h[t + 256*j];
}

__global__ __launch_bounds__(256) void scan_scatter_kernel(
    const float* __restrict__ sv,
    const int*   __restrict__ blkhist,   // [nblk][NBUCK2]
    float4*      __restrict__ sorted,    // [N] out: (x,y,z,bitcast(origIdx))
    float*       __restrict__ rmax,      // [8*nb] out: radial bound per (oct,chunk)
    int*         __restrict__ octStartG, // [9] out: octant starts (+N)
    int N, int nb, int nblk)
{
    __shared__ int startSh[NBUCK2];
    __shared__ int cursor[NBUCK2];
    __shared__ int tsum[256];
    const int t   = threadIdx.x;
    const int blk = blockIdx.x;

    // --- column sums over block rows; thread t owns buckets [t*8, t*8+8) ---
    // two int4 loads per row: coalesced across threads, independent across
    // rows -> pipelines at L2 BW instead of serializing on latency
    int mine[8] = {0,0,0,0,0,0,0,0};
    int tot [8] = {0,0,0,0,0,0,0,0};
    const int4* bh = (const int4*)blkhist;   // row b, bucket t*8 -> b*512 + t*2
#pragma unroll 4
    for (int b = 0; b < nblk; ++b) {
        int4 a = bh[b * 512 + t * 2];
        int4 c = bh[b * 512 + t * 2 + 1];
        tot[0] += a.x; tot[1] += a.y; tot[2] += a.z; tot[3] += a.w;
        tot[4] += c.x; tot[5] += c.y; tot[6] += c.z; tot[7] += c.w;
        if (b < blk) {
            mine[0] += a.x; mine[1] += a.y; mine[2] += a.z; mine[3] += a.w;
            mine[4] += c.x; mine[5] += c.y; mine[6] += c.z; mine[7] += c.w;
        }
    }
    int tsumv = 0;
#pragma unroll
    for (int j = 0; j < 8; ++j) tsumv += tot[j];
    tsum[t] = tsumv;
    __syncthreads();
    // Kogge-Stone inclusive scan over per-thread sums
    for (int d = 1; d < 256; d <<= 1) {
        int u = (t >= d) ? tsum[t - d] : 0;
        __syncthreads();
        tsum[t] += u;
        __syncthreads();
    }
    int running = tsum[t] - tsumv;      // exclusive start of this thread's range
#pragma unroll
    for (int j = 0; j < 8; ++j) {
        startSh[t*8 + j] = running;
        cursor[t*8 + j]  = running + mine[j];   // this block's write base
        running += tot[j];
    }
    __syncthreads();

    if (blk == 0) {
        if (t < 8) octStartG[t] = startSh[t << 8];
        if (t == 8) octStartG[8] = N;
        // rmax[o][k]: radial |p| upper bound for octant-o positions >= oS+64k.
        // Shell found by binary search over startSh; bound = shell upper edge.
        // Top shell (rb==0, |p|^2 may exceed clamp) -> +inf (exact-safe).
        for (int o = 0; o < 8; ++o) {
            int oS = startSh[o << 8];
            int oE = (o < 7) ? startSh[(o + 1) << 8] : N;
            for (int k = t; oS + (k << 6) < oE; k += 256) {
                int pos = oS + (k << 6);
                int lo = 0, hi = RBUCK - 1;
                while (lo < hi) {
                    int mid = (lo + hi + 1) >> 1;
                    if (startSh[(o << 8) + mid] <= pos) lo = mid; else hi = mid - 1;
                }
                rmax[o*nb + k] = (lo == 0) ? 3.0e38f
                                           : sqrtf((float)(RBUCK - lo) * 0.125f);
            }
        }
    }

    // --- scatter own 256 points via LDS cursors ---
    int i = blk * 256 + t;
    if (i < N) {
        float x = sv[3*i], y = sv[3*i+1], z = sv[3*i+2];
        int b = (octant_of(x, y, z) << 8) |
                rbucket_of(fmaf(x, x, fmaf(y, y, z*z)));
        int pos = atomicAdd(&cursor[b], 1);   // LDS atomic
        sorted[pos] = make_float4(x, y, z, __int_as_float(i));
    }
}

template<bool SORTED>
__global__ __launch_bounds__(WAVES * 64) void knn_loss_kernel(
    const float4* __restrict__ pts,    // octant/radial-sorted points (SORTED)
    const float*  __restrict__ rmax,   // [8*nbo] radial bound per (oct,chunk)
    const int*    __restrict__ octStartG, // [9]
    const float*  __restrict__ sv,     // [N,3] original scan vertices
    const float*  __restrict__ tv,     // [M,3]
    const float*  __restrict__ sn,     // [N,3]
    const float*  __restrict__ tn,     // [M,3]
    float* __restrict__ partial,       // [gridDim.x] per-block sums
    int N, int M, float invM, int nbo)
{
    __shared__ float bsum[WAVES];
    const int lane = threadIdx.x & 63;
    const int w    = threadIdx.x >> 6;
    const int m    = blockIdx.x * WAVES + w;
    const bool valid = (m < M);

    float contrib = 0.0f;
    if (valid) {
        const float tvx = tv[3*m], tvy = tv[3*m+1], tvz = tv[3*m+2];
        const float tx2 = tvx*tvx, ty2 = tvy*tvy, tz2 = tvz*tvz;
        const float t2  = tx2 + ty2 + tz2;

        // per-octant opposition energy: contribution of component i to g^2
        // if octant sign is negative (cxn) / positive (cxp).
        const float cxn = (tvx > 0.0f) ? tx2 : 0.0f;
        const float cxp = (tvx < 0.0f) ? tx2 : 0.0f;
        const float cyn = (tvy > 0.0f) ? ty2 : 0.0f;
        const float cyp = (tvy < 0.0f) ? ty2 : 0.0f;
        const float czn = (tvz > 0.0f) ? tz2 : 0.0f;
        const float czp = (tvz < 0.0f) ? tz2 : 0.0f;
        auto g2v = [&](int o) {
            return ((o & 1) ? cxn : cxp) + ((o & 2) ? cyn : cyp)
                 + ((o & 4) ? czn : czp);
        };

        int ob = 0; float bg = 0.0f;
        int prefS = 0; float prefR0 = 0.0f;
        if (SORTED) {
            // most-opposed octant = argmax g^2
            bg = g2v(0);
#pragma unroll
            for (int o = 1; o < 8; ++o) {
                float g2o = g2v(o);
                if (g2o > bg) { bg = g2o; ob = o; }
            }
            // octant starts (9) and chunk-0 radial bounds fetched once into
            // lanes, redistributed via shfl
            if (lane < 9) prefS = octStartG[lane];
            if (lane < 8) prefR0 = rmax[lane * nbo];
        }

        // ---- bootstrap: bitonic-sort 64 points desc by (d2, -idx) ----
        float v; int idx;
        int oS = 0, oE = N;
        {
            int l; bool hasB;
            float px, py, pz;
            if (SORTED) {
                oS = __shfl(prefS, ob); oE = __shfl(prefS, ob + 1);
                l = oS + lane; hasB = l < oE;
                float4 q = pts[hasB ? l : 0];
                px = q.x; py = q.y; pz = q.z; idx = __float_as_int(q.w);
            } else {
                l = lane; hasB = l < N;
                int g = hasB ? l : 0;
                px = sv[3*g]; py = sv[3*g+1]; pz = sv[3*g+2]; idx = l;
            }
            float dx = px - tvx, dy = py - tvy, dz = pz - tvz;
            v = fmaf(dx, dx, fmaf(dy, dy, dz * dz));
            if (!hasB) { v = -1.0f; idx = 0x7FFFFFFF; }
        }
#pragma unroll
        for (int k = 2; k <= 64; k <<= 1) {
#pragma unroll
            for (int j = k >> 1; j > 0; j >>= 1) {
                float ov = __shfl_xor(v, j);
                int   oi = __shfl_xor(idx, j);
                bool up    = ((lane & k) == 0);   // descending segment
                bool lower = ((lane & j) == 0);
                bool mine  = (v > ov) || (v == ov && idx < oi); // total order
                bool keep  = lower ? (up ? mine : !mine) : (up ? !mine : mine);
                if (!keep) { v = ov; idx = oi; }
            }
        }
        // lanes 0..K-1 hold the exact top-K of the bootstrap 64 (sorted desc)
        float eV = (lane < K) ? v : -1.0f;
        int   eI = idx;
        float thr = __shfl(v, K - 1);   // current 15th-largest d2

        // candidate machinery (shared by both paths), processes one 64-chunk
        auto process_chunk = [&](float d2, int oi2, bool has) {
            // >= : equal-d2 candidate with lower original idx must displace
            unsigned long long mb = __ballot(has && (d2 >= thr));
            while (mb) {
                int src = __ffsll(mb) - 1;
                mb &= mb - 1;
                float cv = __shfl(d2, src);
                int   ci = __shfl(oi2, src);
                unsigned long long bb =
                    __ballot((eV > cv) || (eV == cv && eI < ci)) & 0x7FFFull;
                int p = __popcll(bb);
                if (p < K) {   // wave-uniform
                    float uv = __shfl_up(eV, 1);
                    int   ui = __shfl_up(eI, 1);
                    if (lane < K) {
                        if (lane == p)      { eV = cv; eI = ci; }
                        else if (lane > p)  { eV = uv; eI = ui; }
                    }
                    thr = __shfl(eV, K - 1);
                    if (mb) mb &= __ballot(d2 >= thr);
                }
            }
        };

        if (SORTED) {
            // per-octant scan with exact directional bound
            auto scan_octant = [&](int o, int s, int e, int kStart,
                                   float r0, float g) {
                for (int k = kStart; ; ++k) {
                    int pos = s + (k << 6);
                    if (pos >= e) break;
                    float r  = (k == 0) ? r0 : rmax[o*nbo + k];
                    float b2 = fmaf(2.0f*g, r, fmaf(r, r, t2));
                    if (b2 * 1.00001f < thr) break;  // margin: fp-safe skip
                    int i = pos + lane; bool has = i < e;
                    float4 q = pts[has ? i : pos];
                    float dx = q.x - tvx, dy = q.y - tvy, dz = q.z - tvz;
                    float d2 = fmaf(dx, dx, fmaf(dy, dy, dz * dz));
                    process_chunk(d2, __float_as_int(q.w), has);
                }
            };
            // rest of bootstrap octant first (thr is already near-final)
            scan_octant(ob, oS, oE, 1, 0.0f, sqrtf(bg));
            for (int o2 = 0; o2 < 8; ++o2) {
                if (o2 == ob) continue;
                int s2 = __shfl(prefS, o2), e2 = __shfl(prefS, o2 + 1);
                scan_octant(o2, s2, e2, 0, __shfl(prefR0, o2), sqrtf(g2v(o2)));
            }
        } else {
            for (int ib = 64; ib < N; ib += 64) {
                int  i   = ib + lane;
                bool has = (i < N);
                int g = has ? i : 0;
                float dx = sv[3*g] - tvx, dy = sv[3*g+1] - tvy,
                      dz = sv[3*g+2] - tvz;
                float d2 = fmaf(dx, dx, fmaf(dy, dy, dz * dz));
                process_chunk(d2, i, has);
            }
        }

        // ---- epilogue: argmin angle, tie-break by top-k rank (= lane) ----
        const float tnx = tn[3*m], tny = tn[3*m+1], tnz = tn[3*m+2];
        float ang = 3.0e38f;
        int myI = eI;
        if (lane < K && myI != 0x7FFFFFFF) {
            float dot = sn[3*myI]*tnx + sn[3*myI+1]*tny + sn[3*myI+2]*tnz;
            dot = fminf(1.0f, fmaxf(-1.0f, dot));
            ang = acosf(dot) * 57.29577951308232f;   // degrees, matches jnp
        }
        float ba = ang; int br = lane; int bi = myI;
#pragma unroll
        for (int s = 1; s < 16; s <<= 1) {
            float oa  = __shfl_xor(ba, s);
            int   orr = __shfl_xor(br, s);
            int   oi  = __shfl_xor(bi, s);
            bool take = (oa < ba) || (oa == ba && orr < br);
            if (take) { ba = oa; br = orr; bi = oi; }
        }
        if (lane == 0) {
            float dx = sv[3*bi]   - tvx;
            float dy = sv[3*bi+1] - tvy;
            float dz = sv[3*bi+2] - tvz;
            contrib = sqrtf(dx*dx + dy*dy + dz*dz) * invM;
        }
    }

    if (lane == 0) bsum[w] = contrib;
    __syncthreads();
    if (threadIdx.x == 0)
        partial[blockIdx.x] = bsum[0] + bsum[1] + bsum[2] + bsum[3];
}

__global__ __launch_bounds__(256) void reduce_kernel(
    const float* __restrict__ partial, float* __restrict__ out, int n)
{
    __shared__ float sh[4];
    const int lane = threadIdx.x & 63;
    const int w    = threadIdx.x >> 6;
    float s = 0.0f;
    for (int i = threadIdx.x; i < n; i += 256) s += partial[i];
#pragma unroll
    for (int d = 1; d < 64; d <<= 1) s += __shfl_xor(s, d);
    if (lane == 0) sh[w] = s;
    __syncthreads();
    if (threadIdx.x == 0) out[0] = sh[0] + sh[1] + sh[2] + sh[3];
}

extern "C" void kernel_launch(void* const* d_in, const int* in_sizes, int n_in,
                              void* d_out, int out_size, void* d_ws, size_t ws_size,
                              hipStream_t stream) {
    const float* sv = (const float*)d_in[0];   // scan_vertices     [1,N,3]
    const float* tv = (const float*)d_in[1];   // template_vertices [1,M,3]
    const float* sn = (const float*)d_in[2];   // scan_normals      [N,3]
    const float* tn = (const float*)d_in[3];   // template_normals  [M,3]
    // d_in[4] = K_knn (fixed 15, compile-time)

    int N = in_sizes[0] / 3;
    int M = in_sizes[1] / 3;
    int nb = (N + 63) / 64;                    // max chunks per octant
    float* out = (float*)d_out;
    float invM = 1.0f / (float)M;
    int grid  = (M + WAVES - 1) / WAVES;
    int nblk  = (N + 255) / 256;

    // d_ws: [sorted N float4][rmax 8*nb][octStartG 9][blkhist nblk*2048][partial]
    size_t offSorted  = 0;
    size_t offRmax    = offSorted + (size_t)N * sizeof(float4);
    size_t offOct     = (offRmax + (size_t)8 * nb * sizeof(float) + 15) & ~(size_t)15;
    size_t offHist    = (offOct + 9 * sizeof(int) + 15) & ~(size_t)15;
    size_t offPartial = offHist + (size_t)nblk * NBUCK2 * sizeof(int);
    size_t need       = offPartial + (size_t)grid * sizeof(float);

    if (ws_size >= need) {
        float4* sorted   = (float4*)((char*)d_ws + offSorted);
        float*  rmaxp    = (float*) ((char*)d_ws + offRmax);
        int*    octStart = (int*)   ((char*)d_ws + offOct);
        int*    blkhist  = (int*)   ((char*)d_ws + offHist);
        float*  partial  = (float*) ((char*)d_ws + offPartial);

        hist_kernel        <<<nblk, 256, 0, stream>>>(sv, blkhist, N);
        scan_scatter_kernel<<<nblk, 256, 0, stream>>>(sv, blkhist, sorted,
                                                      rmaxp, octStart,
                                                      N, nb, nblk);
        knn_loss_kernel<true><<<grid, WAVES * 64, 0, stream>>>(
            sorted, rmaxp, octStart, sv, tv, sn, tn, partial, N, M, invM, nb);
        reduce_kernel<<<1, 256, 0, stream>>>(partial, out, grid);
    } else if (ws_size >= (size_t)grid * sizeof(float)) {
        float* partial = (float*)d_ws;
        knn_loss_kernel<false><<<grid, WAVES * 64, 0, stream>>>(
            nullptr, nullptr, nullptr, sv, tv, sn, tn, partial, N, M, invM, nb);
        reduce_kernel<<<1, 256, 0, stream>>>(partial, out, grid);
    }
}

// Round 4
// 47.751 us; speedup vs baseline: 1.0534x; 1.0534x over previous
//
#include <hip/hip_runtime.h>
#include <math.h>

// NormalLoss: for each template vertex (M=6890), take the K=15 scan points
// (N=20000) with LARGEST distance, among them pick the min-angle normal
// match, loss = mean ||sv[sel]-tv||.
//
// Round-10 design: octant/radial sort via GLOBAL-ATOMIC RANKS.
//   Ledger r8/r9: any per-thread serial global-load loop (O(N) or O(nblk)
//   per thread) runs ~1 load / ~450 cy when the compiler doesn't pipeline
//   it (42.9 us fused histogram, ~38 us column-sum). This round removes
//   that loop CLASS: position = start[bucket] + rank, where rank is the
//   return of atomicAdd(&ghist[bucket],1) (device-scope, 20K ops over
//   2048 addresses = ~10/address; the banned regime was 1723 ops on ONE
//   address). No column sums, no blkhist, no per-block prefix.
//   Pipeline: memset(ghist,8KB) -> rank (1 atomic + 1 packed store per
//   point) -> scatter (per block: ghist via ONE int4 load-group, local
//   KS scan in LDS, scatter own 256 points; block 0 writes rmax +
//   octStartG) -> knn -> reduce.
//   knn (unchanged since round 8, absmax 0.0 twice): per-wave vertex;
//   exact directional bound max d^2 over octant suffix = r^2+|tv|^2+2 r g
//   (g = opposed-component energy, Cauchy-Schwarz-exact); bitonic
//   bootstrap in argmax-g octant; sorted-insert top-K, thr re-tightened
//   per insert; top shell r=+inf (exact-safe); *1.00001 fp-safe margin.
//   Within-bucket order is an arbitrary permutation -- knn is provably
//   order-independent (total order on (d2,idx); rmax count-only), so the
//   result is bit-identical. reduce: 1-block sum (no atomics on out).

constexpr int K = 15;
constexpr int RBUCK = 256;         // radial shells per octant (0.125-wide |p|^2)
constexpr int NBUCK2 = 8 * RBUCK;  // total buckets
constexpr int WAVES = 4;           // waves (=vertices) per block in main kernel

__device__ __forceinline__ int rbucket_of(float k2) {
    int b = (int)(k2 * 8.0f);
    b = b > (RBUCK - 1) ? (RBUCK - 1) : b;
    return (RBUCK - 1) - b;        // 0 = largest |p| shell
}
__device__ __forceinline__ int octant_of(float x, float y, float z) {
    return (x < 0.0f ? 1 : 0) | (y < 0.0f ? 2 : 0) | (z < 0.0f ? 4 : 0);
}

// rank[i] = within-bucket arrival order; packed (rank<<11)|bucket (rank
// < 2^15, bucket < 2^11 -> 26 bits, positive).
__global__ __launch_bounds__(256) void rank_kernel(
    const float* __restrict__ sv, int* __restrict__ ghist,
    int* __restrict__ pb, int N)
{
    int i = blockIdx.x * 256 + threadIdx.x;
    if (i < N) {
        float x = sv[3*i], y = sv[3*i+1], z = sv[3*i+2];
        int b = (octant_of(x, y, z) << 8) |
                rbucket_of(fmaf(x, x, fmaf(y, y, z*z)));
        int r = atomicAdd(&ghist[b], 1);      // device-scope global atomic
        pb[i] = (r << 11) | b;
    }
}

// Each block: ghist (2 int4/thread, one load-group) -> local KS scan ->
// scatter own 256 points at start[b]+rank. Block 0 also tabulates rmax +
// octStartG from the same scan.
__global__ __launch_bounds__(256) void scatter_kernel(
    const float* __restrict__ sv,
    const int*   __restrict__ ghist,     // [2048] bucket totals
    const int*   __restrict__ pb,        // [N] packed (rank<<11)|bucket
    float4*      __restrict__ sorted,    // [N] out: (x,y,z,bitcast(origIdx))
    float*       __restrict__ rmax,      // [8*nb] out: radial bound per (oct,chunk)
    int*         __restrict__ octStartG, // [9] out: octant starts (+N)
    int N, int nb)
{
    __shared__ int startSh[NBUCK2];
    __shared__ int tsum[256];
    const int t = threadIdx.x;

    // thread t owns buckets [t*8, t*8+8): two int4 loads, ONE group
    const int4* gh4 = (const int4*)ghist;
    int4 a = gh4[t * 2];
    int4 c = gh4[t * 2 + 1];
    int tot[8] = {a.x, a.y, a.z, a.w, c.x, c.y, c.z, c.w};
    int tsumv = 0;
#pragma unroll
    for (int j = 0; j < 8; ++j) tsumv += tot[j];
    tsum[t] = tsumv;
    __syncthreads();
    // Kogge-Stone inclusive scan over per-thread sums
    for (int d = 1; d < 256; d <<= 1) {
        int u = (t >= d) ? tsum[t - d] : 0;
        __syncthreads();
        tsum[t] += u;
        __syncthreads();
    }
    int running = tsum[t] - tsumv;      // exclusive start of this thread's range
#pragma unroll
    for (int j = 0; j < 8; ++j) {
        startSh[t*8 + j] = running;
        running += tot[j];
    }
    __syncthreads();

    if (blockIdx.x == 0) {
        if (t < 8) octStartG[t] = startSh[t << 8];
        if (t == 8) octStartG[8] = N;
        // rmax[o][k]: radial |p| upper bound for octant-o positions >= oS+64k.
        // Shell found by binary search over startSh; bound = shell upper edge.
        // Top shell (rb==0, |p|^2 may exceed clamp) -> +inf (exact-safe).
        for (int o = 0; o < 8; ++o) {
            int oS = startSh[o << 8];
            int oE = (o < 7) ? startSh[(o + 1) << 8] : N;
            for (int k = t; oS + (k << 6) < oE; k += 256) {
                int pos = oS + (k << 6);
                int lo = 0, hi = RBUCK - 1;
                while (lo < hi) {
                    int mid = (lo + hi + 1) >> 1;
                    if (startSh[(o << 8) + mid] <= pos) lo = mid; else hi = mid - 1;
                }
                rmax[o*nb + k] = (lo == 0) ? 3.0e38f
                                           : sqrtf((float)(RBUCK - lo) * 0.125f);
            }
        }
    }

    int i = blockIdx.x * 256 + t;
    if (i < N) {
        float x = sv[3*i], y = sv[3*i+1], z = sv[3*i+2];
        int pbv = pb[i];
        int b   = pbv & (NBUCK2 - 1);
        int r   = pbv >> 11;
        sorted[startSh[b] + r] = make_float4(x, y, z, __int_as_float(i));
    }
}

template<bool SORTED>
__global__ __launch_bounds__(WAVES * 64) void knn_loss_kernel(
    const float4* __restrict__ pts,    // octant/radial-sorted points (SORTED)
    const float*  __restrict__ rmax,   // [8*nbo] radial bound per (oct,chunk)
    const int*    __restrict__ octStartG, // [9]
    const float*  __restrict__ sv,     // [N,3] original scan vertices
    const float*  __restrict__ tv,     // [M,3]
    const float*  __restrict__ sn,     // [N,3]
    const float*  __restrict__ tn,     // [M,3]
    float* __restrict__ partial,       // [gridDim.x] per-block sums
    int N, int M, float invM, int nbo)
{
    __shared__ float bsum[WAVES];
    const int lane = threadIdx.x & 63;
    const int w    = threadIdx.x >> 6;
    const int m    = blockIdx.x * WAVES + w;
    const bool valid = (m < M);

    float contrib = 0.0f;
    if (valid) {
        const float tvx = tv[3*m], tvy = tv[3*m+1], tvz = tv[3*m+2];
        const float tx2 = tvx*tvx, ty2 = tvy*tvy, tz2 = tvz*tvz;
        const float t2  = tx2 + ty2 + tz2;

        // per-octant opposition energy: contribution of component i to g^2
        // if octant sign is negative (cxn) / positive (cxp).
        const float cxn = (tvx > 0.0f) ? tx2 : 0.0f;
        const float cxp = (tvx < 0.0f) ? tx2 : 0.0f;
        const float cyn = (tvy > 0.0f) ? ty2 : 0.0f;
        const float cyp = (tvy < 0.0f) ? ty2 : 0.0f;
        const float czn = (tvz > 0.0f) ? tz2 : 0.0f;
        const float czp = (tvz < 0.0f) ? tz2 : 0.0f;
        auto g2v = [&](int o) {
            return ((o & 1) ? cxn : cxp) + ((o & 2) ? cyn : cyp)
                 + ((o & 4) ? czn : czp);
        };

        int ob = 0; float bg = 0.0f;
        int prefS = 0; float prefR0 = 0.0f;
        if (SORTED) {
            // most-opposed octant = argmax g^2
            bg = g2v(0);
#pragma unroll
            for (int o = 1; o < 8; ++o) {
                float g2o = g2v(o);
                if (g2o > bg) { bg = g2o; ob = o; }
            }
            // octant starts (9) and chunk-0 radial bounds fetched once into
            // lanes, redistributed via shfl
            if (lane < 9) prefS = octStartG[lane];
            if (lane < 8) prefR0 = rmax[lane * nbo];
        }

        // ---- bootstrap: bitonic-sort 64 points desc by (d2, -idx) ----
        float v; int idx;
        int oS = 0, oE = N;
        {
            int l; bool hasB;
            float px, py, pz;
            if (SORTED) {
                oS = __shfl(prefS, ob); oE = __shfl(prefS, ob + 1);
                l = oS + lane; hasB = l < oE;
                float4 q = pts[hasB ? l : 0];
                px = q.x; py = q.y; pz = q.z; idx = __float_as_int(q.w);
            } else {
                l = lane; hasB = l < N;
                int g = hasB ? l : 0;
                px = sv[3*g]; py = sv[3*g+1]; pz = sv[3*g+2]; idx = l;
            }
            float dx = px - tvx, dy = py - tvy, dz = pz - tvz;
            v = fmaf(dx, dx, fmaf(dy, dy, dz * dz));
            if (!hasB) { v = -1.0f; idx = 0x7FFFFFFF; }
        }
#pragma unroll
        for (int k = 2; k <= 64; k <<= 1) {
#pragma unroll
            for (int j = k >> 1; j > 0; j >>= 1) {
                float ov = __shfl_xor(v, j);
                int   oi = __shfl_xor(idx, j);
                bool up    = ((lane & k) == 0);   // descending segment
                bool lower = ((lane & j) == 0);
                bool mine  = (v > ov) || (v == ov && idx < oi); // total order
                bool keep  = lower ? (up ? mine : !mine) : (up ? !mine : mine);
                if (!keep) { v = ov; idx = oi; }
            }
        }
        // lanes 0..K-1 hold the exact top-K of the bootstrap 64 (sorted desc)
        float eV = (lane < K) ? v : -1.0f;
        int   eI = idx;
        float thr = __shfl(v, K - 1);   // current 15th-largest d2

        // candidate machinery (shared by both paths), processes one 64-chunk
        auto process_chunk = [&](float d2, int oi2, bool has) {
            // >= : equal-d2 candidate with lower original idx must displace
            unsigned long long mb = __ballot(has && (d2 >= thr));
            while (mb) {
                int src = __ffsll(mb) - 1;
                mb &= mb - 1;
                float cv = __shfl(d2, src);
                int   ci = __shfl(oi2, src);
                unsigned long long bb =
                    __ballot((eV > cv) || (eV == cv && eI < ci)) & 0x7FFFull;
                int p = __popcll(bb);
                if (p < K) {   // wave-uniform
                    float uv = __shfl_up(eV, 1);
                    int   ui = __shfl_up(eI, 1);
                    if (lane < K) {
                        if (lane == p)      { eV = cv; eI = ci; }
                        else if (lane > p)  { eV = uv; eI = ui; }
                    }
                    thr = __shfl(eV, K - 1);
                    if (mb) mb &= __ballot(d2 >= thr);
                }
            }
        };

        if (SORTED) {
            // per-octant scan with exact directional bound
            auto scan_octant = [&](int o, int s, int e, int kStart,
                                   float r0, float g) {
                for (int k = kStart; ; ++k) {
                    int pos = s + (k << 6);
                    if (pos >= e) break;
                    float r  = (k == 0) ? r0 : rmax[o*nbo + k];
                    float b2 = fmaf(2.0f*g, r, fmaf(r, r, t2));
                    if (b2 * 1.00001f < thr) break;  // margin: fp-safe skip
                    int i = pos + lane; bool has = i < e;
                    float4 q = pts[has ? i : pos];
                    float dx = q.x - tvx, dy = q.y - tvy, dz = q.z - tvz;
                    float d2 = fmaf(dx, dx, fmaf(dy, dy, dz * dz));
                    process_chunk(d2, __float_as_int(q.w), has);
                }
            };
            // rest of bootstrap octant first (thr is already near-final)
            scan_octant(ob, oS, oE, 1, 0.0f, sqrtf(bg));
            for (int o2 = 0; o2 < 8; ++o2) {
                if (o2 == ob) continue;
                int s2 = __shfl(prefS, o2), e2 = __shfl(prefS, o2 + 1);
                scan_octant(o2, s2, e2, 0, __shfl(prefR0, o2), sqrtf(g2v(o2)));
            }
        } else {
            for (int ib = 64; ib < N; ib += 64) {
                int  i   = ib + lane;
                bool has = (i < N);
                int g = has ? i : 0;
                float dx = sv[3*g] - tvx, dy = sv[3*g+1] - tvy,
                      dz = sv[3*g+2] - tvz;
                float d2 = fmaf(dx, dx, fmaf(dy, dy, dz * dz));
                process_chunk(d2, i, has);
            }
        }

        // ---- epilogue: argmin angle, tie-break by top-k rank (= lane) ----
        const float tnx = tn[3*m], tny = tn[3*m+1], tnz = tn[3*m+2];
        float ang = 3.0e38f;
        int myI = eI;
        if (lane < K && myI != 0x7FFFFFFF) {
            float dot = sn[3*myI]*tnx + sn[3*myI+1]*tny + sn[3*myI+2]*tnz;
            dot = fminf(1.0f, fmaxf(-1.0f, dot));
            ang = acosf(dot) * 57.29577951308232f;   // degrees, matches jnp
        }
        float ba = ang; int br = lane; int bi = myI;
#pragma unroll
        for (int s = 1; s < 16; s <<= 1) {
            float oa  = __shfl_xor(ba, s);
            int   orr = __shfl_xor(br, s);
            int   oi  = __shfl_xor(bi, s);
            bool take = (oa < ba) || (oa == ba && orr < br);
            if (take) { ba = oa; br = orr; bi = oi; }
        }
        if (lane == 0) {
            float dx = sv[3*bi]   - tvx;
            float dy = sv[3*bi+1] - tvy;
            float dz = sv[3*bi+2] - tvz;
            contrib = sqrtf(dx*dx + dy*dy + dz*dz) * invM;
        }
    }

    if (lane == 0) bsum[w] = contrib;
    __syncthreads();
    if (threadIdx.x == 0)
        partial[blockIdx.x] = bsum[0] + bsum[1] + bsum[2] + bsum[3];
}

__global__ __launch_bounds__(256) void reduce_kernel(
    const float* __restrict__ partial, float* __restrict__ out, int n)
{
    __shared__ float sh[4];
    const int lane = threadIdx.x & 63;
    const int w    = threadIdx.x >> 6;
    float s = 0.0f;
    for (int i = threadIdx.x; i < n; i += 256) s += partial[i];
#pragma unroll
    for (int d = 1; d < 64; d <<= 1) s += __shfl_xor(s, d);
    if (lane == 0) sh[w] = s;
    __syncthreads();
    if (threadIdx.x == 0) out[0] = sh[0] + sh[1] + sh[2] + sh[3];
}

extern "C" void kernel_launch(void* const* d_in, const int* in_sizes, int n_in,
                              void* d_out, int out_size, void* d_ws, size_t ws_size,
                              hipStream_t stream) {
    const float* sv = (const float*)d_in[0];   // scan_vertices     [1,N,3]
    const float* tv = (const float*)d_in[1];   // template_vertices [1,M,3]
    const float* sn = (const float*)d_in[2];   // scan_normals      [N,3]
    const float* tn = (const float*)d_in[3];   // template_normals  [M,3]
    // d_in[4] = K_knn (fixed 15, compile-time)

    int N = in_sizes[0] / 3;
    int M = in_sizes[1] / 3;
    int nb = (N + 63) / 64;                    // max chunks per octant
    float* out = (float*)d_out;
    float invM = 1.0f / (float)M;
    int grid  = (M + WAVES - 1) / WAVES;
    int nblk  = (N + 255) / 256;

    // d_ws: [sorted N float4][rmax 8*nb][octStartG 9][ghist 2048][pb N][partial]
    size_t offSorted  = 0;
    size_t offRmax    = offSorted + (size_t)N * sizeof(float4);
    size_t offOct     = (offRmax + (size_t)8 * nb * sizeof(float) + 15) & ~(size_t)15;
    size_t offGhist   = (offOct + 9 * sizeof(int) + 15) & ~(size_t)15;
    size_t offPb      = offGhist + (size_t)NBUCK2 * sizeof(int);
    size_t offPartial = offPb + (size_t)N * sizeof(int);
    size_t need       = offPartial + (size_t)grid * sizeof(float);

    if (ws_size >= need) {
        float4* sorted   = (float4*)((char*)d_ws + offSorted);
        float*  rmaxp    = (float*) ((char*)d_ws + offRmax);
        int*    octStart = (int*)   ((char*)d_ws + offOct);
        int*    ghist    = (int*)   ((char*)d_ws + offGhist);
        int*    pb       = (int*)   ((char*)d_ws + offPb);
        float*  partial  = (float*) ((char*)d_ws + offPartial);

        hipMemsetAsync(ghist, 0, (size_t)NBUCK2 * sizeof(int), stream);
        rank_kernel   <<<nblk, 256, 0, stream>>>(sv, ghist, pb, N);
        scatter_kernel<<<nblk, 256, 0, stream>>>(sv, ghist, pb, sorted,
                                                 rmaxp, octStart, N, nb);
        knn_loss_kernel<true><<<grid, WAVES * 64, 0, stream>>>(
            sorted, rmaxp, octStart, sv, tv, sn, tn, partial, N, M, invM, nb);
        reduce_kernel<<<1, 256, 0, stream>>>(partial, out, grid);
    } else if (ws_size >= (size_t)grid * sizeof(float)) {
        float* partial = (float*)d_ws;
        knn_loss_kernel<false><<<grid, WAVES * 64, 0, stream>>>(
            nullptr, nullptr, nullptr, sv, tv, sn, tn, partial, N, M, invM, nb);
        reduce_kernel<<<1, 256, 0, stream>>>(partial, out, grid);
    }
}